// Round 3
// baseline (132.604 us; speedup 1.0000x reference)
//
#include <hip/hip_runtime.h>

#define NN 2048
#define KK 8
#define BB 32
#define TT 20
#define GG 4              // blocks per batch
#define CHUNK (NN / GG)   // 512 oscillators per block

// Shard each batch over GG blocks. Exchange medium is `out` itself
// (out[t+1][b][:] is exactly the step-t+1 phase row): stores/loads use
// agent-scope (sc0/sc1) atomics -> write-through to MALL, bypass the
// non-coherent per-XCD L2s. Step barrier = per-(batch,step) counter in d_ws.
__global__ __launch_bounds__(CHUNK) void osci_kernel(
    const float* __restrict__ coupling,   // [B,N,K]
    const float* __restrict__ phase0,     // [B,N]
    const float* __restrict__ omega,      // [B,N]
    const int*   __restrict__ conn,       // [N,K]
    float*       __restrict__ out,        // [T+1,B,N]
    unsigned*    __restrict__ flags)      // [BB*TT], zeroed per graph replay
{
    const int b   = blockIdx.x & (BB - 1);   // batch
    const int c   = blockIdx.x >> 5;         // chunk 0..3 (stride-32 ids -> same XCD)
    const int tid = threadIdx.x;
    const int i   = c * CHUNK + tid;         // own oscillator

    __shared__ float ph_buf[NN];             // full phase row, state t

    // ---- prologue: full row t=0 into LDS, own state into regs ----
    #pragma unroll
    for (int r = 0; r < GG; ++r) {
        const int idx = tid + r * CHUNK;
        ph_buf[idx] = phase0[b * NN + idx];
    }

    float ph = phase0[b * NN + i];
    out[(size_t)b * NN + i] = ph;            // out[0,b,i]; plain store (never exchanged)
    const float om = omega[b * NN + i];

    int   cidx[KK];
    float w[KK];
    float inv_n;
    {
        int   jj[KK];
        float vv[KK];
        #pragma unroll
        for (int k = 0; k < KK; ++k) {
            jj[k] = conn[i * KK + k];
            vv[k] = coupling[((size_t)b * NN + i) * KK + k];
        }
        // last-wins scatter dedup: entry k vanishes if any k2>k hits same column;
        // n = count of surviving nonzero dense-row entries
        int cnt = 0;
        #pragma unroll
        for (int k = 0; k < KK; ++k) {
            bool over = false;
            #pragma unroll
            for (int k2 = k + 1; k2 < KK; ++k2) over = over || (jj[k2] == jj[k]);
            if (over) vv[k] = 0.0f;
            if (vv[k] != 0.0f) ++cnt;
        }
        #pragma unroll
        for (int k = 0; k < KK; ++k) { cidx[k] = jj[k]; w[k] = vv[k]; }
        inv_n = 1.0f / (float)cnt;           // cnt >= 1 always (last write survives)
    }
    __syncthreads();

    // ---- time steps ----
    #pragma unroll 1
    for (int t = 0; t < TT; ++t) {
        float* outrow = out + ((size_t)(t + 1) * BB + b) * NN;

        float acc = 0.0f;
        #pragma unroll
        for (int k = 0; k < KK; ++k) {
            const float pj = ph_buf[cidx[k]];
            acc += w[k] * __sinf(pj - ph);     // same per-element math as before
        }
        const float pn = ph + acc * inv_n + om;  // eps=1, ANNEAL=0
        ph = pn;
        // write-through to MALL so sibling blocks (other XCDs) see it
        __hip_atomic_store(&outrow[i], pn, __ATOMIC_RELAXED, __HIP_MEMORY_SCOPE_AGENT);

        if (t == TT - 1) break;                  // last row written; no sync needed

        __syncthreads();                         // drains vmcnt (stores at MALL) AND
                                                 // ensures all waves done gathering ph_buf
        if (tid == 0) {
            unsigned* f = &flags[b * TT + t];
            __hip_atomic_fetch_add(f, 1u, __ATOMIC_ACQ_REL, __HIP_MEMORY_SCOPE_AGENT);
            while (__hip_atomic_load(f, __ATOMIC_ACQUIRE, __HIP_MEMORY_SCOPE_AGENT) < GG) {}
        }
        __syncthreads();

        // reload sibling chunks from MALL; own chunk from register
        #pragma unroll
        for (int r = 0; r < GG; ++r) {
            if (r == c) continue;                // wave-uniform branch
            const int idx = tid + r * CHUNK;
            ph_buf[idx] = __hip_atomic_load(&outrow[idx], __ATOMIC_RELAXED,
                                            __HIP_MEMORY_SCOPE_AGENT);
        }
        ph_buf[i] = pn;
        __syncthreads();                         // reload visible before next gathers
    }
}

extern "C" void kernel_launch(void* const* d_in, const int* in_sizes, int n_in,
                              void* d_out, int out_size, void* d_ws, size_t ws_size,
                              hipStream_t stream) {
    const float* coupling = (const float*)d_in[0];   // [B,N,K]
    const float* phase0   = (const float*)d_in[1];   // [B,N]
    const float* omega    = (const float*)d_in[2];   // [B,N]
    const int*   conn     = (const int*)d_in[3];     // [N,K]
    float* out = (float*)d_out;                      // [T+1,B,N]

    // per-(batch,step) arrival counters; re-zeroed inside the captured graph
    hipMemsetAsync(d_ws, 0, BB * TT * sizeof(unsigned), stream);
    osci_kernel<<<BB * GG, CHUNK, 0, stream>>>(coupling, phase0, omega, conn, out,
                                               (unsigned*)d_ws);
}

// Round 4
// 79.622 us; speedup vs baseline: 1.6654x; 1.6654x over previous
//
#include <hip/hip_runtime.h>

#define NN 2048
#define KK 8
#define BB 32
#define TT 20

__global__ __launch_bounds__(1024) void osci_kernel(
    const float* __restrict__ coupling,   // [B,N,K]
    const float* __restrict__ phase0,     // [B,N]
    const float* __restrict__ omega,      // [B,N]
    const int*   __restrict__ conn,       // [N,K]
    float*       __restrict__ out)        // [T+1,B,N]
{
    const int b   = blockIdx.x;
    const int tid = threadIdx.x;

    // double-buffered (sin,cos) table: buf0 = sc_buf[0..NN), buf1 = sc_buf[NN..2NN)
    // buf1 accesses fold to ds_read_b64/ds_write_b64 offset:16384 immediates
    __shared__ float2 sc_buf[2 * NN];     // 32 KiB

    // per-thread state: 2 oscillators each (2*1024 = 2048)
    int   cidx[2][KK];
    float w[2][KK];
    float inv_n[2];
    float om[2];
    float ph[2];
    float si[2], ci[2];

    for (int t = 0; t < 2; ++t) {
        const int i = tid + t * 1024;
        float p = phase0[b * NN + i];
        ph[t] = p;
        float s, c;
        __sincosf(p, &s, &c);
        si[t] = s; ci[t] = c;
        sc_buf[i] = make_float2(s, c);
        out[(size_t)b * NN + i] = p;          // out[0, b, i] = phase0
        om[t] = omega[b * NN + i];

        int   jj[KK];
        float vv[KK];
        #pragma unroll
        for (int k = 0; k < KK; ++k) {
            jj[k] = conn[i * KK + k];
            vv[k] = coupling[((size_t)b * NN + i) * KK + k];
        }
        // last-wins scatter dedup: entry k vanishes if any k2>k hits same column;
        // n = count of surviving nonzero dense-row entries
        int cnt = 0;
        #pragma unroll
        for (int k = 0; k < KK; ++k) {
            bool over = false;
            #pragma unroll
            for (int k2 = k + 1; k2 < KK; ++k2) over = over || (jj[k2] == jj[k]);
            if (over) vv[k] = 0.0f;
            if (vv[k] != 0.0f) ++cnt;
        }
        #pragma unroll
        for (int k = 0; k < KK; ++k) { cidx[t][k] = jj[k]; w[t][k] = vv[k]; }
        inv_n[t] = 1.0f / (float)cnt;         // cnt >= 1 always (last write survives)
    }
    __syncthreads();   // setup: full drain once is fine

    float* outp = out + ((size_t)BB + b) * NN;   // &out[1][b][0]

    #pragma unroll 1
    for (int sp = 0; sp < TT; sp += 2) {
        // ---- even step: read buf0, write buf1 ----
        #pragma unroll
        for (int t = 0; t < 2; ++t) {
            const int i = tid + t * 1024;
            // reference decomposition: Cs = Σ w·sin(φ_j), Cc = Σ w·cos(φ_j)
            float cs = 0.0f, cc = 0.0f;
            #pragma unroll
            for (int k = 0; k < KK; ++k) {
                const float2 v = sc_buf[cidx[t][k]];        // ds_read_b64 offset:0
                cs += w[t][k] * v.x;
                cc += w[t][k] * v.y;
            }
            // delta = (Cs·c_i − Cc·s_i)/n   (eps=1, ANNEAL=0)
            const float pn = ph[t] + (cs * ci[t] - cc * si[t]) * inv_n[t] + om[t];
            ph[t] = pn;
            float sn, cn;
            __sincosf(pn, &sn, &cn);
            si[t] = sn; ci[t] = cn;
            sc_buf[NN + i] = make_float2(sn, cn);           // ds_write_b64 offset:16384
            outp[i] = pn;                                   // fire-and-forget HBM store
        }
        // LDS-only barrier: own ds_reads (WAR) + ds_writes (RAW) complete; no vmcnt drain
        asm volatile("s_waitcnt lgkmcnt(0)" ::: "memory");
        __builtin_amdgcn_s_barrier();
        asm volatile("" ::: "memory");
        outp += (size_t)BB * NN;

        // ---- odd step: read buf1, write buf0 ----
        #pragma unroll
        for (int t = 0; t < 2; ++t) {
            const int i = tid + t * 1024;
            float cs = 0.0f, cc = 0.0f;
            #pragma unroll
            for (int k = 0; k < KK; ++k) {
                const float2 v = sc_buf[NN + cidx[t][k]];   // ds_read_b64 offset:16384
                cs += w[t][k] * v.x;
                cc += w[t][k] * v.y;
            }
            const float pn = ph[t] + (cs * ci[t] - cc * si[t]) * inv_n[t] + om[t];
            ph[t] = pn;
            float sn, cn;
            __sincosf(pn, &sn, &cn);
            si[t] = sn; ci[t] = cn;
            sc_buf[i] = make_float2(sn, cn);                // ds_write_b64 offset:0
            outp[i] = pn;
        }
        asm volatile("s_waitcnt lgkmcnt(0)" ::: "memory");
        __builtin_amdgcn_s_barrier();
        asm volatile("" ::: "memory");
        outp += (size_t)BB * NN;
    }
}

extern "C" void kernel_launch(void* const* d_in, const int* in_sizes, int n_in,
                              void* d_out, int out_size, void* d_ws, size_t ws_size,
                              hipStream_t stream) {
    const float* coupling = (const float*)d_in[0];   // [B,N,K]
    const float* phase0   = (const float*)d_in[1];   // [B,N]
    const float* omega    = (const float*)d_in[2];   // [B,N]
    const int*   conn     = (const int*)d_in[3];     // [N,K]
    float* out = (float*)d_out;                      // [T+1,B,N]

    osci_kernel<<<BB, 1024, 0, stream>>>(coupling, phase0, omega, conn, out);
}